// Round 2
// baseline (824.524 us; speedup 1.0000x reference)
//
#include <hip/hip_runtime.h>

typedef __attribute__((ext_vector_type(8))) short short8;
typedef __attribute__((ext_vector_type(4))) float f32x4;

#define NNODES 55296
#define DOUT 256

__device__ __forceinline__ float bf2f(unsigned short h) {
    union { unsigned u; float f; } x;
    x.u = ((unsigned)h) << 16;
    return x.f;
}
__device__ __forceinline__ unsigned short f2bf(float f) {
    union { float f; unsigned u; } x;
    x.f = f;
    unsigned u = x.u;
    return (unsigned short)((u + 0x7fffu + ((u >> 16) & 1u)) >> 16);
}

// load 8 consecutive channel values as float, from f32 or bf16 storage
__device__ __forceinline__ void load8(const float* p, float* o) {
    float4 a = *(const float4*)p;
    float4 b = *(const float4*)(p + 4);
    o[0] = a.x; o[1] = a.y; o[2] = a.z; o[3] = a.w;
    o[4] = b.x; o[5] = b.y; o[6] = b.z; o[7] = b.w;
}
__device__ __forceinline__ void load8(const unsigned short* p, float* o) {
    uint4 v = *(const uint4*)p;
    const unsigned short* u = (const unsigned short*)&v;
#pragma unroll
    for (int i = 0; i < 8; ++i) o[i] = bf2f(u[i]);
}

__device__ __forceinline__ void storev(float* p, float v) { *p = v; }
__device__ __forceinline__ void storev(unsigned short* p, float v) { *p = f2bf(v); }

// Wt[d][k] = bf16( k < C ? W_self[k][d] : W_neigh[k-C][d] ); d in [0,256), k in [0,2C)
__global__ void build_wt(const float* __restrict__ Ws,
                         const float* __restrict__ Wn,
                         unsigned short* __restrict__ Wt, int C) {
    int K2 = 2 * C;
    int idx = blockIdx.x * 256 + threadIdx.x;
    if (idx >= 256 * K2) return;
    int d = idx / K2;
    int k = idx - d * K2;
    float v = (k < C) ? Ws[(size_t)k * DOUT + d] : Wn[(size_t)(k - C) * DOUT + d];
    Wt[idx] = f2bf(v);
}

// One workgroup: 64 rows x 256 output cols. 4 waves, each wave: 16 rows x 256 cols.
// LDS tile A[64][2C] (bf16): cols [0,C) = h(self), cols [C,2C) = mean of 4 neighbors.
// XOR swizzle on 16B granularity to avoid LDS bank conflicts on ds_read_b128.
template <int C, typename TIN, typename TOUT>
__global__ __launch_bounds__(256) void sage_layer(
    const TIN* __restrict__ hin,              // [B*N][C]
    const int* __restrict__ nbr,              // [N][4]
    const unsigned short* __restrict__ Wt,    // [256][2C] bf16 bits
    const float* __restrict__ bias,           // [256] f32
    TOUT* __restrict__ out) {                 // [B*N][256]
    constexpr int K2 = 2 * C;
    constexpr int ROWB = K2 * 2;  // bytes per LDS row
    __shared__ unsigned short Asm[64 * K2];
    char* Ab = (char*)Asm;

    const int tid = threadIdx.x;
    const int m0 = blockIdx.x * 64;
    const int b = m0 / NNODES;         // all 64 rows share b (NNODES % 64 == 0)
    const int n0 = m0 - b * NNODES;
    const size_t baseRow = (size_t)b * NNODES;

    // ---- stage A tile ----
    {
        const int row = tid >> 2;  // 0..63
        const int q = tid & 3;
        constexpr int CH = C / 4;  // channel elems handled per (row,q)
        const int kq = q * CH;
        const TIN* src = hin + (size_t)(m0 + row) * C + kq;
        const int4 nb = *(const int4*)(nbr + (size_t)(n0 + row) * 4);
        const TIN* p0 = hin + (baseRow + nb.x) * (size_t)C + kq;
        const TIN* p1 = hin + (baseRow + nb.y) * (size_t)C + kq;
        const TIN* p2 = hin + (baseRow + nb.z) * (size_t)C + kq;
        const TIN* p3 = hin + (baseRow + nb.w) * (size_t)C + kq;
#pragma unroll
        for (int e = 0; e < CH; e += 8) {
            float s[8];
            load8(src + e, s);
            __attribute__((aligned(16))) unsigned short res[8];
#pragma unroll
            for (int i = 0; i < 8; ++i) res[i] = f2bf(s[i]);
            int off = (row * ROWB + (kq + e) * 2) ^ ((row & 7) << 4);
            *(uint4*)(Ab + off) = *(const uint4*)res;

            float a0[8], a1[8], a2[8], a3[8];
            load8(p0 + e, a0);
            load8(p1 + e, a1);
            load8(p2 + e, a2);
            load8(p3 + e, a3);
#pragma unroll
            for (int i = 0; i < 8; ++i)
                res[i] = f2bf((a0[i] + a1[i] + a2[i] + a3[i]) * 0.25f);
            off = (row * ROWB + (C + kq + e) * 2) ^ ((row & 7) << 4);
            *(uint4*)(Ab + off) = *(const uint4*)res;
        }
    }
    __syncthreads();

    const int lane = tid & 63;
    const int w = tid >> 6;   // wave 0..3 -> row-tile
    const int lr = lane & 15; // A row / B col / D col
    const int lg = lane >> 4; // k-group / D row-group

    f32x4 acc[16];
    const f32x4 zero = {0.f, 0.f, 0.f, 0.f};
#pragma unroll
    for (int j = 0; j < 16; ++j) acc[j] = zero;

    const int arow = w * 16 + lr;
    for (int kk = 0; kk < K2 / 32; ++kk) {
        const int k0 = kk * 32 + lg * 8;
        const int aoff = (arow * ROWB + k0 * 2) ^ ((arow & 7) << 4);
        const short8 a = *(const short8*)(Ab + aoff);
#pragma unroll
        for (int j = 0; j < 16; ++j) {
            const short8 bfr = *(const short8*)(Wt + (size_t)(j * 16 + lr) * K2 + k0);
            acc[j] = __builtin_amdgcn_mfma_f32_16x16x32_bf16(a, bfr, acc[j], 0, 0, 0);
        }
    }

    // ---- epilogue: bias + relu + store ----
#pragma unroll
    for (int j = 0; j < 16; ++j) {
        const int col = j * 16 + lr;
        const float bv = bias[col];
#pragma unroll
        for (int r = 0; r < 4; ++r) {
            const int row = w * 16 + lg * 4 + r;
            float v = acc[j][r] + bv;
            v = fmaxf(v, 0.0f);
            storev(out + (size_t)(m0 + row) * DOUT + col, v);
        }
    }
}

extern "C" void kernel_launch(void* const* d_in, const int* in_sizes, int n_in,
                              void* d_out, int out_size, void* d_ws, size_t ws_size,
                              hipStream_t stream) {
    const float* x = (const float*)d_in[0];
    const int* nbr = (const int*)d_in[1];
    const float* Ws1 = (const float*)d_in[2];
    const float* Wn1 = (const float*)d_in[3];
    const float* b1 = (const float*)d_in[4];
    const float* Ws2 = (const float*)d_in[5];
    const float* Wn2 = (const float*)d_in[6];
    const float* b2 = (const float*)d_in[7];
    float* out = (float*)d_out;

    const int B = in_sizes[0] / (NNODES * 128);  // 4
    const int M = B * NNODES;                    // 221184

    char* ws = (char*)d_ws;
    unsigned short* h1 = (unsigned short*)ws;  // [M][256] bf16
    unsigned short* Wt1 = (unsigned short*)(ws + (size_t)M * DOUT * 2);
    unsigned short* Wt2 = Wt1 + 256 * 256;

    build_wt<<<256, 256, 0, stream>>>(Ws1, Wn1, Wt1, 128);
    build_wt<<<512, 256, 0, stream>>>(Ws2, Wn2, Wt2, 256);

    const int mblocks = M / 64;  // 3456
    sage_layer<128, float, unsigned short><<<mblocks, 256, 0, stream>>>(x, nbr, Wt1, b1, h1);
    sage_layer<256, unsigned short, float><<<mblocks, 256, 0, stream>>>(h1, nbr, Wt2, b2, out);
}

// Round 3
// 414.030 us; speedup vs baseline: 1.9915x; 1.9915x over previous
//
#include <hip/hip_runtime.h>

typedef __attribute__((ext_vector_type(8))) short short8;
typedef __attribute__((ext_vector_type(4))) float f32x4;

#define NNODES 55296
#define DOUT 256

__device__ __forceinline__ float bf2f(unsigned short h) {
    union { unsigned u; float f; } x; x.u = ((unsigned)h) << 16; return x.f;
}
__device__ __forceinline__ unsigned short f2bf(float f) {
    union { float f; unsigned u; } x; x.f = f;
    return (unsigned short)((x.u + 0x7fffu + ((x.u >> 16) & 1u)) >> 16);
}

__device__ __forceinline__ void storev(float* p, float v) { *p = v; }
__device__ __forceinline__ void storev(unsigned short* p, float v) { *p = f2bf(v); }

// ---- fragment helpers: 8 consecutive k-elems -> bf16 short8 ----
__device__ __forceinline__ short8 frag_self(const float* p) {
    float4 a = *(const float4*)p, b = *(const float4*)(p + 4);
    union { short8 s; unsigned short u[8]; } r;
    r.u[0] = f2bf(a.x); r.u[1] = f2bf(a.y); r.u[2] = f2bf(a.z); r.u[3] = f2bf(a.w);
    r.u[4] = f2bf(b.x); r.u[5] = f2bf(b.y); r.u[6] = f2bf(b.z); r.u[7] = f2bf(b.w);
    return r.s;
}
__device__ __forceinline__ short8 frag_self(const unsigned short* p) {
    return *(const short8*)p;
}
__device__ __forceinline__ void acc8(const float* p, float* o) {
    float4 a = *(const float4*)p, b = *(const float4*)(p + 4);
    o[0] += a.x; o[1] += a.y; o[2] += a.z; o[3] += a.w;
    o[4] += b.x; o[5] += b.y; o[6] += b.z; o[7] += b.w;
}
__device__ __forceinline__ void acc8(const unsigned short* p, float* o) {
    uint4 v = *(const uint4*)p;
    const unsigned short* u = (const unsigned short*)&v;
#pragma unroll
    for (int i = 0; i < 8; ++i) o[i] += bf2f(u[i]);
}
template <typename TIN>
__device__ __forceinline__ short8 frag_mean4(const TIN* p0, const TIN* p1,
                                             const TIN* p2, const TIN* p3) {
    float s[8] = {0.f, 0.f, 0.f, 0.f, 0.f, 0.f, 0.f, 0.f};
    acc8(p0, s); acc8(p1, s); acc8(p2, s); acc8(p3, s);
    union { short8 s8; unsigned short u[8]; } r;
#pragma unroll
    for (int i = 0; i < 8; ++i) r.u[i] = f2bf(s[i] * 0.25f);
    return r.s8;
}

// Wt[d][k] = bf16( k < C ? W_self[k][d] : W_neigh[k-C][d] ); d in [0,256), k in [0,2C)
__global__ void build_wt(const float* __restrict__ Ws,
                         const float* __restrict__ Wn,
                         unsigned short* __restrict__ Wt, int C) {
    int K2 = 2 * C;
    int idx = blockIdx.x * 256 + threadIdx.x;
    if (idx >= 256 * K2) return;
    int d = idx / K2;
    int k = idx - d * K2;
    float v = (k < C) ? Ws[(size_t)k * DOUT + d] : Wn[(size_t)(k - C) * DOUT + d];
    Wt[idx] = f2bf(v);
}

// v3: weights persistent in LDS (128KB, XOR-swizzled), A direct global->reg
// fragments (self half + on-the-fly 4-neighbor mean), no inner-loop barriers.
// 8 waves/block; each wave owns a 64-row x 128-col output tile.
template <int C, typename TIN, typename TOUT>
__global__ __launch_bounds__(512, 2) void sage_v3(
    const TIN* __restrict__ hin,              // [B*N][C]
    const int* __restrict__ nbr,              // [N][4]
    const unsigned short* __restrict__ Wt,    // [256][2C] bf16 bits (d-major)
    const float* __restrict__ bias,           // [256] f32
    TOUT* __restrict__ out) {                 // [B*N][256]
    constexpr int K2 = 2 * C;
    constexpr int ROWB = K2 * 2;              // bytes per Wt row
    constexpr int LCOLS = 131072 / ROWB;      // cols resident in LDS: 256 (L1) / 128 (L2)
    constexpr int CG = LCOLS / 128;           // wave col-groups: 2 (L1) / 1 (L2)
    constexpr int RG = 8 / CG;                // wave row-groups: 4 (L1) / 8 (L2)
    extern __shared__ char Bs[];              // 128 KB

    const int tid = threadIdx.x;
    const int gcol0 = blockIdx.y * LCOLS;

    // ---- stage B (weights) into LDS, once; XOR swizzle (col&7)<<4 ----
    {
        const char* src = (const char*)(Wt + (size_t)gcol0 * K2);
#pragma unroll
        for (int i = 0; i < 131072 / (512 * 16); ++i) {
            int byt = (i * 512 + tid) * 16;
            uint4 v = *(const uint4*)(src + byt);
            int c = byt / ROWB;
            *(uint4*)(Bs + (byt ^ ((c & 7) << 4))) = v;
        }
    }
    __syncthreads();

    const int l = tid & 63;
    const int w = tid >> 6;
    const int rowg = w / CG;
    const int colb = (w % CG) * 128;          // local col base within LDS
    const int lr = l & 15, lg = l >> 4;

    const int rowbase = blockIdx.x * (RG * 64) + rowg * 64;
    const int bb = rowbase / NNODES;          // batch (tiles never straddle)
    const int n0 = rowbase - bb * NNODES;
    const size_t bbase = (size_t)bb * NNODES;

    // per-m byte offsets (32-bit) for self row + 4 neighbor rows, incl. lg*8 k-chunk
    unsigned soff[4], noff[4][4];
#pragma unroll
    for (int m = 0; m < 4; ++m) {
        int r = m * 16 + lr;
        soff[m] = (unsigned)(((rowbase + r) * (size_t)C + lg * 8) * sizeof(TIN));
        int4 nb = *(const int4*)(nbr + (size_t)(n0 + r) * 4);
        noff[m][0] = (unsigned)(((bbase + nb.x) * C + lg * 8) * sizeof(TIN));
        noff[m][1] = (unsigned)(((bbase + nb.y) * C + lg * 8) * sizeof(TIN));
        noff[m][2] = (unsigned)(((bbase + nb.z) * C + lg * 8) * sizeof(TIN));
        noff[m][3] = (unsigned)(((bbase + nb.w) * C + lg * 8) * sizeof(TIN));
    }
    const char* hb = (const char*)hin;

    f32x4 acc[4][8];
#pragma unroll
    for (int m = 0; m < 4; ++m)
#pragma unroll
        for (int j = 0; j < 8; ++j) acc[m][j] = (f32x4){0.f, 0.f, 0.f, 0.f};

    // ---- main loop over K; no barriers ----
#pragma unroll
    for (int kk = 0; kk < K2 / 32; ++kk) {
        const int k0 = kk * 32;
        short8 a[4];
        if (k0 < C) {
            const unsigned kb = k0 * sizeof(TIN);
#pragma unroll
            for (int m = 0; m < 4; ++m)
                a[m] = frag_self((const TIN*)(hb + soff[m] + kb));
        } else {
            const unsigned kb = (k0 - C) * sizeof(TIN);
#pragma unroll
            for (int m = 0; m < 4; ++m)
                a[m] = frag_mean4((const TIN*)(hb + noff[m][0] + kb),
                                  (const TIN*)(hb + noff[m][1] + kb),
                                  (const TIN*)(hb + noff[m][2] + kb),
                                  (const TIN*)(hb + noff[m][3] + kb));
        }
#pragma unroll
        for (int j = 0; j < 8; ++j) {
            const int c = colb + j * 16 + lr;
            const short8 bf = *(const short8*)(
                Bs + ((c * ROWB + (k0 + lg * 8) * 2) ^ ((l & 7) << 4)));
#pragma unroll
            for (int m = 0; m < 4; ++m)
                acc[m][j] = __builtin_amdgcn_mfma_f32_16x16x32_bf16(a[m], bf, acc[m][j], 0, 0, 0);
        }
    }

    // ---- epilogue: bias + relu + store ----
#pragma unroll
    for (int j = 0; j < 8; ++j) {
        const int gcol = gcol0 + colb + j * 16 + lr;
        const float bv = bias[gcol];
#pragma unroll
        for (int m = 0; m < 4; ++m) {
#pragma unroll
            for (int r = 0; r < 4; ++r) {
                const int row = rowbase + m * 16 + lg * 4 + r;
                storev(out + (size_t)row * DOUT + gcol, fmaxf(acc[m][j][r] + bv, 0.f));
            }
        }
    }
}

extern "C" void kernel_launch(void* const* d_in, const int* in_sizes, int n_in,
                              void* d_out, int out_size, void* d_ws, size_t ws_size,
                              hipStream_t stream) {
    const float* x = (const float*)d_in[0];
    const int* nbr = (const int*)d_in[1];
    const float* Ws1 = (const float*)d_in[2];
    const float* Wn1 = (const float*)d_in[3];
    const float* b1 = (const float*)d_in[4];
    const float* Ws2 = (const float*)d_in[5];
    const float* Wn2 = (const float*)d_in[6];
    const float* b2 = (const float*)d_in[7];
    float* out = (float*)d_out;

    const int B = in_sizes[0] / (NNODES * 128);  // 4
    const int M = B * NNODES;                    // 221184

    char* ws = (char*)d_ws;
    unsigned short* h1 = (unsigned short*)ws;  // [M][256] bf16
    unsigned short* Wt1 = (unsigned short*)(ws + (size_t)M * DOUT * 2);
    unsigned short* Wt2 = Wt1 + 256 * 256;

    build_wt<<<256, 256, 0, stream>>>(Ws1, Wn1, Wt1, 128);
    build_wt<<<512, 256, 0, stream>>>(Ws2, Wn2, Wt2, 256);

    // allow 128KB dynamic LDS (idempotent; safe outside capture semantics)
    hipFuncSetAttribute((const void*)sage_v3<128, float, unsigned short>,
                        hipFuncAttributeMaxDynamicSharedMemorySize, 131072);
    hipFuncSetAttribute((const void*)sage_v3<256, unsigned short, float>,
                        hipFuncAttributeMaxDynamicSharedMemorySize, 131072);

    // layer 1: 8 waves = 4 rowgroups x 2 colgroups; block = 256 rows x 256 cols
    sage_v3<128, float, unsigned short>
        <<<dim3(M / 256, 1), 512, 131072, stream>>>(x, nbr, Wt1, b1, h1);
    // layer 2: 8 waves = 8 rowgroups; block = 512 rows x 128 cols (y = col half)
    sage_v3<256, unsigned short, float>
        <<<dim3(M / 512, 2), 512, 131072, stream>>>(h1, nbr, Wt2, b2, out);
}